// Round 10
// baseline (126.136 us; speedup 1.0000x reference)
//
#include <hip/hip_runtime.h>
#include <math.h>

#define NQ   10
#define DIM  1024
#define NB   10
#define NPTS 128
#define S2   0.70710678118654752440f

#define TS 32
#define KC 64
#define KSPLIT (DIM / KC)       // 16
#define NBLK_RED 64             // reduce_final grid

#define WPB 8                   // waves (=points) per states block
#define TP  22                  // transpose buffer pitch (float2 units)

typedef float f2 __attribute__((ext_vector_type(2)));   // (re, im)

// ---------------------------------------------------------------------------
// helpers
// ---------------------------------------------------------------------------
__device__ __forceinline__ f2 cmul_cs(f2 v, float c, float s) {
    return (f2){ v.x * c - v.y * s, v.x * s + v.y * c };
}

#define H_PAIR(i0, i1) {                              \
    const f2 a = v[i0], b = v[i1];                    \
    v[i0] = (a + b) * S2;                             \
    v[i1] = (a - b) * S2; }

#define RY_PAIR(i0, i1, c, s) {                       \
    const f2 a = v[i0], b = v[i1];                    \
    v[i0] = c * a - s * b;                            \
    v[i1] = s * a + c * b; }

// ---------------------------------------------------------------------------
// Kernel A: simulate psi(x) = F(x, params)|0>.
// 512-thread blocks = 8 INDEPENDENT waves = 8 points; wave-private LDS, no
// barriers in the main loop (single barrier after shared param staging).
// Per-wave layout (identical math to proven round-9 kernel, absmax 0.0):
//   canonical  : d = lane*16 + m   (reg bits d[3:0], lane bits d[9:4])
//   transposed : d = m*64  + lane  (reg bits d[9:6], lane bits d[5:0])
// Qubit q acts on d-bit 9-q. 8/10 butterfly levels register-local; qubits
// 4,5 via __shfl_xor; transposes through interleaved float2 buffer pitch 22
// (b128 writes / b64 reads both at bank minimum). RZ/CRZ cis tables built
// on the fly per circuit block (1 sincos/lane, wave-synchronous).
// State is f2-packed (re,im) so H/RY butterflies emit v_pk_* (2 flops/inst).
// ---------------------------------------------------------------------------
__global__ __launch_bounds__(512)
void states_kernel(const float* __restrict__ data,
                   const float* __restrict__ params,
                   float2* __restrict__ psi,
                   double* __restrict__ acc,
                   int* __restrict__ cnt)
{
    __shared__ float2 T[WPB][64 * TP];     // 8 x 11264 B transpose buffers
    __shared__ float  sX  [WPB][NB * NQ];  // per-point data angles
    __shared__ float  sB  [WPB][NB];       // per-point -0.5*sum(x) per block
    __shared__ float2 crzT[WPB][4 * 17];   // per-point CRZ reg-part cis (pitch 17)
    __shared__ float2 rzT [WPB][16];       // per-point RZ reg-part cis
    __shared__ float  sRyC[NB * NQ];       // shared params: cos(ry/2)
    __shared__ float  sRyS[NB * NQ];       //                sin(ry/2)
    __shared__ float  sCrz[NB * NQ];       //                crz angles

    const int tid  = threadIdx.x;
    const int wv   = tid >> 6;             // wave = point-within-block
    const int lane = tid & 63;
    const int pt   = blockIdx.x * WPB + wv;

    if (blockIdx.x == 0 && tid == 0) { acc[0] = 0.0; acc[1] = 0.0; cnt[0] = 0; }

    // ---- shared param staging (whole block), then one barrier ----
    if (tid < NB * NQ) {
        const int j = tid / NQ, q = tid - j * NQ;
        float s, c;
        __sincosf(0.5f * params[j * 2 * NQ + q], &s, &c);
        sRyC[tid] = c; sRyS[tid] = s;
        sCrz[tid] = params[j * 2 * NQ + NQ + q];
    }
    // ---- wave-private staging (wave-synchronous, no barrier needed) ----
    for (int i = lane; i < NB * NQ; i += 64)
        sX[wv][i] = data[pt * (NB * NQ) + i];
    if (lane < NB) {
        float s = 0.f;
        #pragma unroll
        for (int q = 0; q < NQ; ++q) s += sX[wv][lane * NQ + q];
        sB[wv][lane] = -0.5f * s;
    }
    __syncthreads();

    // ---- state init: |0...0> ----
    f2 v[16];
    #pragma unroll
    for (int m = 0; m < 16; ++m) v[m] = (f2){0.f, 0.f};
    if (lane == 0) v[0].x = 1.f;

    const int trow = (lane >> 4) * TP + (lane & 15);   // transposed addr base

    for (int j = 0; j < NB; ++j) {
        const int j10 = j * NQ;

        // ===== on-the-fly cis tables for this block (wave-synchronous) =====
        {
            const int bc = lane >> 4, m = lane & 15;
            const float m3 = (float)((m >> 3) & 1), m2 = (float)((m >> 2) & 1);
            const float m1 = (float)((m >> 1) & 1), m0 = (float)(m & 1);
            const float b4 = (float)((bc >> 1) & 1), b9 = (float)(bc & 1);
            const float g = sCrz[j10 + 5] * b4 * (m3 - 0.5f)
                          + sCrz[j10 + 6] * m3 * (m2 - 0.5f)
                          + sCrz[j10 + 7] * m2 * (m1 - 0.5f)
                          + sCrz[j10 + 8] * m1 * (m0 - 0.5f)
                          + sCrz[j10 + 9] * m0 * (b9 - 0.5f);
            float s, c;
            __sincosf(g, &s, &c);
            crzT[wv][bc * 17 + m] = make_float2(c, s);
            if (lane < 16) {
                float Tt = 0.f;
                #pragma unroll
                for (int q = 0; q < 4; ++q)
                    Tt += (float)((lane >> (3 - q)) & 1) * sX[wv][j10 + q];
                float ss, cc;
                __sincosf(Tt, &ss, &cc);
                rzT[wv][lane] = make_float2(cc, ss);
            }
        }

        // ===== H: canonical reg bits 3..0 (qubits 6..9) =====
        #pragma unroll
        for (int b = 3; b >= 0; --b) {
            const int bit = 1 << b;
            #pragma unroll
            for (int m = 0; m < 16; ++m)
                if (!(m & bit)) { H_PAIR(m, m | bit) }
        }
        // ===== H: lane bits 0,1 (qubits 5,4) via shuffle =====
        #pragma unroll
        for (int l = 0; l < 2; ++l) {
            const float sg = ((lane >> l) & 1) ? -1.f : 1.f;
            #pragma unroll
            for (int m = 0; m < 16; ++m) {
                const f2 u = { __shfl_xor(v[m].x, 1 << l, 64),
                               __shfl_xor(v[m].y, 1 << l, 64) };
                v[m] = (u + sg * v[m]) * S2;
            }
        }
        // ===== transpose canonical -> transposed =====
        #pragma unroll
        for (int k = 0; k < 8; ++k)
            *(float4*)&T[wv][lane * TP + 2 * k] =
                make_float4(v[2*k].x, v[2*k].y, v[2*k+1].x, v[2*k+1].y);
        #pragma unroll
        for (int m = 0; m < 16; ++m) {
            const float2 t = T[wv][m * (4 * TP) + trow];
            v[m] = (f2){t.x, t.y};
        }
        // ===== H: transposed reg bits 3..0 (qubits 0..3) =====
        #pragma unroll
        for (int b = 3; b >= 0; --b) {
            const int bit = 1 << b;
            #pragma unroll
            for (int m = 0; m < 16; ++m)
                if (!(m & bit)) { H_PAIR(m, m | bit) }
        }

        // ===== RZ diagonal (transposed) =====
        {
            float lp = sB[wv][j];
            #pragma unroll
            for (int q = 4; q < NQ; ++q)
                lp = fmaf((float)((lane >> (9 - q)) & 1), sX[wv][j10 + q], lp);
            float sl, cl;
            __sincosf(lp, &sl, &cl);
            #pragma unroll
            for (int m = 0; m < 16; ++m) {
                const float2 z = rzT[wv][m];
                const float rc = cl * z.x - sl * z.y;
                const float rs = cl * z.y + sl * z.x;
                v[m] = cmul_cs(v[m], rc, rs);
            }
        }

        // ===== RY: transposed reg bits (qubit q <-> bit 3-q), q=0..3 =====
        #pragma unroll
        for (int q = 0; q < 4; ++q) {
            const float c = sRyC[j10 + q], s = sRyS[j10 + q];
            const int bit = 1 << (3 - q);
            #pragma unroll
            for (int m = 0; m < 16; ++m)
                if (!(m & bit)) { RY_PAIR(m, m | bit, c, s) }
        }
        // ===== transpose back transposed -> canonical =====
        #pragma unroll
        for (int m = 0; m < 16; ++m)
            T[wv][m * (4 * TP) + trow] = make_float2(v[m].x, v[m].y);
        #pragma unroll
        for (int k = 0; k < 8; ++k) {
            const float4 t = *(const float4*)&T[wv][lane * TP + 2 * k];
            v[2*k]   = (f2){t.x, t.y};
            v[2*k+1] = (f2){t.z, t.w};
        }
        // ===== RY: canonical reg bits (qubit q <-> bit 9-q), q=6..9 =====
        #pragma unroll
        for (int q = 6; q < 10; ++q) {
            const float c = sRyC[j10 + q], s = sRyS[j10 + q];
            const int bit = 1 << (9 - q);
            #pragma unroll
            for (int m = 0; m < 16; ++m)
                if (!(m & bit)) { RY_PAIR(m, m | bit, c, s) }
        }
        // ===== RY: lane bits 0,1 (qubits 5,4) via shuffle =====
        #pragma unroll
        for (int l = 0; l < 2; ++l) {
            const float c = sRyC[j10 + 5 - l];
            const float s = sRyS[j10 + 5 - l];
            const float ss = ((lane >> l) & 1) ? s : -s;
            #pragma unroll
            for (int m = 0; m < 16; ++m) {
                const f2 u = { __shfl_xor(v[m].x, 1 << l, 64),
                               __shfl_xor(v[m].y, 1 << l, 64) };
                v[m] = c * v[m] + ss * u;
            }
        }

        // ===== CRZ ring diagonal (canonical) =====
        {
            float cm = 0.f;
            #pragma unroll
            for (int q = 0; q <= 4; ++q) {
                const float bc_ = (float)((lane >> (5 - q)) & 1);
                const float bt_ = (float)((lane >> (4 - q)) & 1);
                cm += sCrz[j10 + q] * bc_ * (bt_ - 0.5f);
            }
            float sc, cc;
            __sincosf(cm, &sc, &cc);
            const int bc = ((lane & 1) << 1) | ((lane >> 5) & 1);
            const float2* __restrict__ rcp = &crzT[wv][bc * 17];
            #pragma unroll
            for (int m = 0; m < 16; ++m) {
                const float2 z = rcp[m];
                const float rr = cc * z.x - sc * z.y;
                const float ri = cc * z.y + sc * z.x;
                v[m] = cmul_cs(v[m], rr, ri);
            }
        }
    }

    // ---- write out (canonical) ----
    float2* o = psi + (size_t)pt * DIM + lane * 16;
    #pragma unroll
    for (int k = 0; k < 8; ++k)
        *(float4*)&o[2 * k] = make_float4(v[2*k].x, v[2*k].y, v[2*k+1].x, v[2*k+1].y);
}

// ---------------------------------------------------------------------------
// Kernel B: tiled complex Gram (proven rounds 2/5/6/8/9). 32x32 tile x 16
// K-chunks = 256 blocks. Coalesced float4 staging; A broadcast / Bt <=2-way
// LDS reads; 2x2 register accumulator per thread.
// ---------------------------------------------------------------------------
__global__ __launch_bounds__(256)
void gram_kernel(const float2* __restrict__ psi, float2* __restrict__ Gpart)
{
    __shared__ float2 A [TS][KC + 2];   // pitch 66 float2
    __shared__ float2 Bt[KC][TS + 2];   // pitch 34 float2

    const int tid  = threadIdx.x;
    const int bx   = blockIdx.x;
    const int ks   = bx & 15;
    const int tile = bx >> 4;
    const int ti   = tile >> 2, tj = tile & 3;
    const int kbase = ks * KC;

    #pragma unroll
    for (int it = 0; it < 2; ++it) {
        const int slot = it * 256 + tid;
        const int row  = slot >> 4;          // 0..31
        const int kq   = (slot & 15) << 2;   // 0,4,...,60
        const float4* sa = (const float4*)(psi + (ti * TS + row) * DIM + kbase + kq);
        const float4 a01 = sa[0], a23 = sa[1];
        *(float4*)&A[row][kq]     = a01;
        *(float4*)&A[row][kq + 2] = a23;
        const float4* sb = (const float4*)(psi + (tj * TS + row) * DIM + kbase + kq);
        const float4 b01 = sb[0], b23 = sb[1];
        Bt[kq + 0][row] = make_float2(b01.x, b01.y);
        Bt[kq + 1][row] = make_float2(b01.z, b01.w);
        Bt[kq + 2][row] = make_float2(b23.x, b23.y);
        Bt[kq + 3][row] = make_float2(b23.z, b23.w);
    }
    __syncthreads();

    const int ty = tid >> 4, tx = tid & 15;
    float g00r = 0.f, g00i = 0.f, g01r = 0.f, g01i = 0.f;
    float g10r = 0.f, g10i = 0.f, g11r = 0.f, g11i = 0.f;

    #pragma unroll 4
    for (int k = 0; k < KC; k += 2) {
        const float4 a0 = *(const float4*)&A[2 * ty    ][k];
        const float4 a1 = *(const float4*)&A[2 * ty + 1][k];
        const float4 b0 = *(const float4*)&Bt[k    ][2 * tx];
        const float4 b1 = *(const float4*)&Bt[k + 1][2 * tx];
        g00r += a0.x * b0.x + a0.y * b0.y;  g00i += a0.x * b0.y - a0.y * b0.x;
        g01r += a0.x * b0.z + a0.y * b0.w;  g01i += a0.x * b0.w - a0.y * b0.z;
        g10r += a1.x * b0.x + a1.y * b0.y;  g10i += a1.x * b0.y - a1.y * b0.x;
        g11r += a1.x * b0.z + a1.y * b0.w;  g11i += a1.x * b0.w - a1.y * b0.z;
        g00r += a0.z * b1.x + a0.w * b1.y;  g00i += a0.z * b1.y - a0.w * b1.x;
        g01r += a0.z * b1.z + a0.w * b1.w;  g01i += a0.z * b1.w - a0.w * b1.z;
        g10r += a1.z * b1.x + a1.w * b1.y;  g10i += a1.z * b1.y - a1.w * b1.x;
        g11r += a1.z * b1.z + a1.w * b1.w;  g11i += a1.z * b1.w - a1.w * b1.z;
    }

    float2* gp = Gpart + ks * (NPTS * NPTS);
    const int gr0 = ti * TS + 2 * ty, gc0 = tj * TS + 2 * tx;
    gp[(gr0    ) * NPTS + gc0    ] = make_float2(g00r, g00i);
    gp[(gr0    ) * NPTS + gc0 + 1] = make_float2(g01r, g01i);
    gp[(gr0 + 1) * NPTS + gc0    ] = make_float2(g10r, g10i);
    gp[(gr0 + 1) * NPTS + gc0 + 1] = make_float2(g11r, g11i);
}

// ---------------------------------------------------------------------------
// Kernel C: sum K-partials (coalesced), K = |G|^2, reduce polarity & sum(K^2);
// last-finishing block (atomic counter, proven) writes the scalar.
// ---------------------------------------------------------------------------
__global__ __launch_bounds__(256)
void reduce_final(const float2* __restrict__ Gpart,
                  const float* __restrict__ labels,
                  double* __restrict__ acc,
                  int* __restrict__ cnt,
                  float* __restrict__ out)
{
    const int idx = blockIdx.x * 256 + threadIdx.x;   // 0..16383
    float gr = 0.f, gi = 0.f;
    #pragma unroll
    for (int p = 0; p < KSPLIT; ++p) {
        const float2 g = Gpart[p * (NPTS * NPTS) + idx];
        gr += g.x; gi += g.y;
    }
    const int i  = idx >> 7;
    const int jj = idx & (NPTS - 1);
    const float K = gr * gr + gi * gi;
    double pol = (double)(labels[i] * labels[jj]) * (double)K;
    double k2  = (double)K * (double)K;
    #pragma unroll
    for (int off = 1; off < 64; off <<= 1) {
        pol += __shfl_xor(pol, off, 64);
        k2  += __shfl_xor(k2,  off, 64);
    }
    __shared__ double sp[4], sk[4];
    const int wv = threadIdx.x >> 6;
    if ((threadIdx.x & 63) == 0) { sp[wv] = pol; sk[wv] = k2; }
    __syncthreads();
    if (threadIdx.x == 0) {
        atomicAdd(&acc[0], sp[0] + sp[1] + sp[2] + sp[3]);
        atomicAdd(&acc[1], sk[0] + sk[1] + sk[2] + sk[3]);
        __threadfence();
        const int done = atomicAdd(cnt, 1);
        if (done == NBLK_RED - 1) {
            const double p  = atomicAdd(&acc[0], 0.0);   // atomic read
            const double s2 = atomicAdd(&acc[1], 0.0);
            double sumL2 = 0.0;
            for (int t = 0; t < NPTS; ++t) {
                const double l = (double)labels[t];
                sumL2 += l * l;
            }
            out[0] = (float)(p / (sumL2 * sqrt(s2)));
        }
    }
}

// ---------------------------------------------------------------------------
extern "C" void kernel_launch(void* const* d_in, const int* in_sizes, int n_in,
                              void* d_out, int out_size, void* d_ws, size_t ws_size,
                              hipStream_t stream)
{
    const float* data   = (const float*)d_in[0];   // [128,100]
    const float* labels = (const float*)d_in[1];   // [128]
    const float* params = (const float*)d_in[2];   // [10,2,10]
    float* out = (float*)d_out;

    float2* psi   = (float2*)d_ws;                                   // 1 MiB
    float2* Gpart = (float2*)((char*)d_ws + (size_t)(1u << 20));     // 2 MiB
    double* acc   = (double*)((char*)d_ws + (size_t)(3u << 20));     // 16 B
    int*    cnt   = (int*)   ((char*)d_ws + (size_t)(3u << 20) + 16);

    states_kernel<<<NPTS / WPB, 512, 0, stream>>>(data, params, psi, acc, cnt);
    gram_kernel<<<256, 256, 0, stream>>>(psi, Gpart);
    reduce_final<<<NBLK_RED, 256, 0, stream>>>(Gpart, labels, acc, cnt, out);
}

// Round 11
// 88.420 us; speedup vs baseline: 1.4266x; 1.4266x over previous
//
#include <hip/hip_runtime.h>
#include <math.h>

#define NQ   10
#define DIM  1024
#define NB   10
#define NPTS 128
#define S2   0.70710678118654752440f

#define TS 32
#define KC 64
#define KSPLIT (DIM / KC)       // 16
#define NBLK_RED 64             // reduce_final grid

typedef float f2 __attribute__((ext_vector_type(2)));   // (re, im)

// ---------------------------------------------------------------------------
// helpers
// ---------------------------------------------------------------------------
__device__ __forceinline__ f2 cmul(f2 a, f2 b) {
    return (f2){a.x * b.x - a.y * b.y, a.x * b.y + a.y * b.x};
}

// ---------------------------------------------------------------------------
// Kernel A: simulate psi(x) = F(x, params)|0>. 256 threads = 1 point/block.
// KEY ALGEBRA: per encoding block, (
//   ry_layer(theta) . rz_layer(x) . h_layer ) = tensor_q U_q with
//   U_q = RY(theta_q) RZ(x_q) H   (single 2x2 complex butterfly per qubit)
// so each block is ONE 10-level butterfly sweep + the CRZ diagonal.
// Layouts ping-pong (ONE transpose + ONE barrier per block):
//   A: d = w*256 + lane*4 + m   (m bits = d[1:0] -> qubits 8,9)
//   B: d = m*256 + lane*4 + w   (m bits = d[9:8] -> qubits 0,1)
// lane bits d[7:2] -> qubits 2..7 (shuffle levels, both layouts).
// Even blocks: A-local(9,8), shuffle, transpose->B, B-local(1,0), CRZ-B.
// Odd  blocks: B-local(1,0), shuffle, transpose->A, A-local(8,9), CRZ-A.
// NB=10 even -> final layout A (canonical write-out).
// Chain ~11 dependent rounds/block vs 24 in the H/RZ/RY formulation.
// ---------------------------------------------------------------------------
__global__ __launch_bounds__(256)
void states_kernel(const float* __restrict__ data,
                   const float* __restrict__ params,
                   float2* __restrict__ psi,
                   double* __restrict__ acc,
                   int* __restrict__ cnt)
{
    __shared__ f2    Tb[2][16 * 64];    // ping-pong transpose buffers (8 KB ea)
    __shared__ f2    UT[NB * NQ * 4];   // U-matrices: [j][q][4]
    __shared__ float sCrz[NB * NQ];     // CRZ angles

    const int tid  = threadIdx.x;
    const int w    = tid >> 6;          // 0..3
    const int lane = tid & 63;
    const int pt   = blockIdx.x;

    if (pt == 0 && tid == 0) { acc[0] = 0.0; acc[1] = 0.0; cnt[0] = 0; }

    // ---- staging: U_q = RY(th)RZ(x)H per (block, qubit); CRZ angles ----
    if (tid < NB * NQ) {
        const int j = tid / NQ, q = tid - j * NQ;
        const float th = params[j * 2 * NQ + q];
        float c, s;
        __sincosf(0.5f * th, &s, &c);
        const float x = data[pt * (NB * NQ) + tid];
        float cx, sx;
        __sincosf(0.5f * x, &sx, &cx);
        const float al = (c - s) * S2, be = (c + s) * S2;
        f2* u = &UT[tid * 4];
        u[0] = (f2){ al * cx, -be * sx};
        u[1] = (f2){ be * cx, -al * sx};
        u[2] = (f2){ be * cx,  al * sx};
        u[3] = (f2){-al * cx, -be * sx};
        sCrz[tid] = params[j * 2 * NQ + NQ + q];
    }
    __syncthreads();

    // ---- |0...0> : d=0 is thread (w=0, lane=0), m=0 ----
    f2 v[4];
    #pragma unroll
    for (int m = 0; m < 4; ++m) v[m] = (f2){0.f, 0.f};
    if (tid == 0) v[0] = (f2){1.f, 0.f};

    // lane-resident CRZ bits (d[7:2])
    const float B2 = (float)( lane       & 1), B3 = (float)((lane >> 1) & 1);
    const float B4 = (float)((lane >> 2) & 1), B5 = (float)((lane >> 3) & 1);
    const float B6 = (float)((lane >> 4) & 1), B7 = (float)((lane >> 5) & 1);

    #define LOAD_U(j, q) \
        const f2* _u = &UT[((j) * NQ + (q)) * 4]; \
        const f2 u0 = _u[0], u1 = _u[1], u2 = _u[2], u3 = _u[3];

    #define APPLY_LOCAL(j, q, bit) { \
        LOAD_U(j, q) \
        _Pragma("unroll") \
        for (int m = 0; m < 4; ++m) if (!(m & (bit))) { \
            const f2 a0 = v[m], a1 = v[m | (bit)]; \
            v[m]         = cmul(u0, a0) + cmul(u1, a1); \
            v[m | (bit)] = cmul(u2, a0) + cmul(u3, a1); \
        } }

    #define APPLY_SHUFFLE(j, q, mb) { \
        LOAD_U(j, q) \
        const bool hi = lane & (mb); \
        const f2 cv = hi ? u3 : u0; \
        const f2 cp = hi ? u2 : u1; \
        _Pragma("unroll") \
        for (int m = 0; m < 4; ++m) { \
            const f2 p = { __shfl_xor(v[m].x, (mb), 64), \
                           __shfl_xor(v[m].y, (mb), 64) }; \
            v[m] = cmul(cv, v[m]) + cmul(cp, p); \
        } }

    #define TRANSPOSE(buf) { \
        f2* T = Tb[buf]; \
        _Pragma("unroll") \
        for (int m = 0; m < 4; ++m) T[(w * 4 + m) * 64 + lane] = v[m]; \
        __syncthreads(); \
        f2 nv0 = T[(0 * 4 + w) * 64 + lane]; \
        f2 nv1 = T[(1 * 4 + w) * 64 + lane]; \
        f2 nv2 = T[(2 * 4 + w) * 64 + lane]; \
        f2 nv3 = T[(3 * 4 + w) * 64 + lane]; \
        v[0] = nv0; v[1] = nv1; v[2] = nv2; v[3] = nv3; }

    // CRZ: hiIsAmp=true  -> layout B (hi2 = m, lo2 = w)
    //      hiIsAmp=false -> layout A (hi2 = w, lo2 = m)
    #define APPLY_CRZ(j, hiIsAmp) { \
        const float* phi = &sCrz[(j) * NQ]; \
        const float laneOnly = phi[2] * B7 * (B6 - 0.5f) \
                             + phi[3] * B6 * (B5 - 0.5f) \
                             + phi[4] * B5 * (B4 - 0.5f) \
                             + phi[5] * B4 * (B3 - 0.5f) \
                             + phi[6] * B3 * (B2 - 0.5f); \
        _Pragma("unroll") \
        for (int m = 0; m < 4; ++m) { \
            const int hi2 = (hiIsAmp) ? m : w; \
            const int lo2 = (hiIsAmp) ? w : m; \
            const float b9 = (float)((hi2 >> 1) & 1), b8 = (float)(hi2 & 1); \
            const float b1 = (float)((lo2 >> 1) & 1), b0 = (float)(lo2 & 1); \
            const float ph = laneOnly \
                           + phi[0] * b9 * (b8 - 0.5f) \
                           + phi[1] * b8 * (B7 - 0.5f) \
                           + phi[7] * B2 * (b1 - 0.5f) \
                           + phi[8] * b1 * (b0 - 0.5f) \
                           + phi[9] * b0 * (b9 - 0.5f); \
            float sc, cc; \
            __sincosf(ph, &sc, &cc); \
            v[m] = cmul(v[m], (f2){cc, sc}); \
        } }

    #pragma unroll
    for (int jj = 0; jj < NB / 2; ++jj) {
        const int je = 2 * jj;          // even block: layout A at entry
        // local A: qubit 9 (bit0 of d -> reg bit 1? d-bit0 = m-bit0 -> pairs m, m|1)
        APPLY_LOCAL(je, 9, 1)
        APPLY_LOCAL(je, 8, 2)
        APPLY_SHUFFLE(je, 7, 1)
        APPLY_SHUFFLE(je, 6, 2)
        APPLY_SHUFFLE(je, 5, 4)
        APPLY_SHUFFLE(je, 4, 8)
        APPLY_SHUFFLE(je, 3, 16)
        APPLY_SHUFFLE(je, 2, 32)
        TRANSPOSE(0)                    // A -> B
        APPLY_LOCAL(je, 1, 1)           // d-bit8 = m-bit0
        APPLY_LOCAL(je, 0, 2)           // d-bit9 = m-bit1
        APPLY_CRZ(je, true)

        const int jo = je + 1;          // odd block: layout B at entry
        APPLY_LOCAL(jo, 1, 1)
        APPLY_LOCAL(jo, 0, 2)
        APPLY_SHUFFLE(jo, 7, 1)
        APPLY_SHUFFLE(jo, 6, 2)
        APPLY_SHUFFLE(jo, 5, 4)
        APPLY_SHUFFLE(jo, 4, 8)
        APPLY_SHUFFLE(jo, 3, 16)
        APPLY_SHUFFLE(jo, 2, 32)
        TRANSPOSE(1)                    // B -> A
        APPLY_LOCAL(jo, 9, 1)
        APPLY_LOCAL(jo, 8, 2)
        APPLY_CRZ(jo, false)
    }

    // ---- write out (layout A: d = w*256 + lane*4 + m) ----
    float2* o = psi + (size_t)pt * DIM + w * 256 + lane * 4;
    *(float4*)&o[0] = make_float4(v[0].x, v[0].y, v[1].x, v[1].y);
    *(float4*)&o[2] = make_float4(v[2].x, v[2].y, v[3].x, v[3].y);
}

// ---------------------------------------------------------------------------
// Kernel B: tiled complex Gram (proven rounds 2/5/6/8/9/10). 32x32 tile x 16
// K-chunks = 256 blocks. Coalesced float4 staging; A broadcast / Bt <=2-way
// LDS reads; 2x2 register accumulator per thread.
// ---------------------------------------------------------------------------
__global__ __launch_bounds__(256)
void gram_kernel(const float2* __restrict__ psi, float2* __restrict__ Gpart)
{
    __shared__ float2 A [TS][KC + 2];   // pitch 66 float2
    __shared__ float2 Bt[KC][TS + 2];   // pitch 34 float2

    const int tid  = threadIdx.x;
    const int bx   = blockIdx.x;
    const int ks   = bx & 15;
    const int tile = bx >> 4;
    const int ti   = tile >> 2, tj = tile & 3;
    const int kbase = ks * KC;

    #pragma unroll
    for (int it = 0; it < 2; ++it) {
        const int slot = it * 256 + tid;
        const int row  = slot >> 4;          // 0..31
        const int kq   = (slot & 15) << 2;   // 0,4,...,60
        const float4* sa = (const float4*)(psi + (ti * TS + row) * DIM + kbase + kq);
        const float4 a01 = sa[0], a23 = sa[1];
        *(float4*)&A[row][kq]     = a01;
        *(float4*)&A[row][kq + 2] = a23;
        const float4* sb = (const float4*)(psi + (tj * TS + row) * DIM + kbase + kq);
        const float4 b01 = sb[0], b23 = sb[1];
        Bt[kq + 0][row] = make_float2(b01.x, b01.y);
        Bt[kq + 1][row] = make_float2(b01.z, b01.w);
        Bt[kq + 2][row] = make_float2(b23.x, b23.y);
        Bt[kq + 3][row] = make_float2(b23.z, b23.w);
    }
    __syncthreads();

    const int ty = tid >> 4, tx = tid & 15;
    float g00r = 0.f, g00i = 0.f, g01r = 0.f, g01i = 0.f;
    float g10r = 0.f, g10i = 0.f, g11r = 0.f, g11i = 0.f;

    #pragma unroll 4
    for (int k = 0; k < KC; k += 2) {
        const float4 a0 = *(const float4*)&A[2 * ty    ][k];
        const float4 a1 = *(const float4*)&A[2 * ty + 1][k];
        const float4 b0 = *(const float4*)&Bt[k    ][2 * tx];
        const float4 b1 = *(const float4*)&Bt[k + 1][2 * tx];
        g00r += a0.x * b0.x + a0.y * b0.y;  g00i += a0.x * b0.y - a0.y * b0.x;
        g01r += a0.x * b0.z + a0.y * b0.w;  g01i += a0.x * b0.w - a0.y * b0.z;
        g10r += a1.x * b0.x + a1.y * b0.y;  g10i += a1.x * b0.y - a1.y * b0.x;
        g11r += a1.x * b0.z + a1.y * b0.w;  g11i += a1.x * b0.w - a1.y * b0.z;
        g00r += a0.z * b1.x + a0.w * b1.y;  g00i += a0.z * b1.y - a0.w * b1.x;
        g01r += a0.z * b1.z + a0.w * b1.w;  g01i += a0.z * b1.w - a0.w * b1.z;
        g10r += a1.z * b1.x + a1.w * b1.y;  g10i += a1.z * b1.y - a1.w * b1.x;
        g11r += a1.z * b1.z + a1.w * b1.w;  g11i += a1.z * b1.w - a1.w * b1.z;
    }

    float2* gp = Gpart + ks * (NPTS * NPTS);
    const int gr0 = ti * TS + 2 * ty, gc0 = tj * TS + 2 * tx;
    gp[(gr0    ) * NPTS + gc0    ] = make_float2(g00r, g00i);
    gp[(gr0    ) * NPTS + gc0 + 1] = make_float2(g01r, g01i);
    gp[(gr0 + 1) * NPTS + gc0    ] = make_float2(g10r, g10i);
    gp[(gr0 + 1) * NPTS + gc0 + 1] = make_float2(g11r, g11i);
}

// ---------------------------------------------------------------------------
// Kernel C: sum K-partials (coalesced), K = |G|^2, reduce polarity & sum(K^2);
// last-finishing block (atomic counter, proven) writes the scalar.
// ---------------------------------------------------------------------------
__global__ __launch_bounds__(256)
void reduce_final(const float2* __restrict__ Gpart,
                  const float* __restrict__ labels,
                  double* __restrict__ acc,
                  int* __restrict__ cnt,
                  float* __restrict__ out)
{
    const int idx = blockIdx.x * 256 + threadIdx.x;   // 0..16383
    float gr = 0.f, gi = 0.f;
    #pragma unroll
    for (int p = 0; p < KSPLIT; ++p) {
        const float2 g = Gpart[p * (NPTS * NPTS) + idx];
        gr += g.x; gi += g.y;
    }
    const int i  = idx >> 7;
    const int jj = idx & (NPTS - 1);
    const float K = gr * gr + gi * gi;
    double pol = (double)(labels[i] * labels[jj]) * (double)K;
    double k2  = (double)K * (double)K;
    #pragma unroll
    for (int off = 1; off < 64; off <<= 1) {
        pol += __shfl_xor(pol, off, 64);
        k2  += __shfl_xor(k2,  off, 64);
    }
    __shared__ double sp[4], sk[4];
    const int wv = threadIdx.x >> 6;
    if ((threadIdx.x & 63) == 0) { sp[wv] = pol; sk[wv] = k2; }
    __syncthreads();
    if (threadIdx.x == 0) {
        atomicAdd(&acc[0], sp[0] + sp[1] + sp[2] + sp[3]);
        atomicAdd(&acc[1], sk[0] + sk[1] + sk[2] + sk[3]);
        __threadfence();
        const int done = atomicAdd(cnt, 1);
        if (done == NBLK_RED - 1) {
            const double p  = atomicAdd(&acc[0], 0.0);   // atomic read
            const double s2 = atomicAdd(&acc[1], 0.0);
            double sumL2 = 0.0;
            for (int t = 0; t < NPTS; ++t) {
                const double l = (double)labels[t];
                sumL2 += l * l;
            }
            out[0] = (float)(p / (sumL2 * sqrt(s2)));
        }
    }
}

// ---------------------------------------------------------------------------
extern "C" void kernel_launch(void* const* d_in, const int* in_sizes, int n_in,
                              void* d_out, int out_size, void* d_ws, size_t ws_size,
                              hipStream_t stream)
{
    const float* data   = (const float*)d_in[0];   // [128,100]
    const float* labels = (const float*)d_in[1];   // [128]
    const float* params = (const float*)d_in[2];   // [10,2,10]
    float* out = (float*)d_out;

    float2* psi   = (float2*)d_ws;                                   // 1 MiB
    float2* Gpart = (float2*)((char*)d_ws + (size_t)(1u << 20));     // 2 MiB
    double* acc   = (double*)((char*)d_ws + (size_t)(3u << 20));     // 16 B
    int*    cnt   = (int*)   ((char*)d_ws + (size_t)(3u << 20) + 16);

    states_kernel<<<NPTS, 256, 0, stream>>>(data, params, psi, acc, cnt);
    gram_kernel<<<256, 256, 0, stream>>>(psi, Gpart);
    reduce_final<<<NBLK_RED, 256, 0, stream>>>(Gpart, labels, acc, cnt, out);
}

// Round 12
// 87.680 us; speedup vs baseline: 1.4386x; 1.0084x over previous
//
#include <hip/hip_runtime.h>
#include <math.h>

#define NQ   10
#define DIM  1024
#define NB   10
#define NPTS 128
#define S2   0.70710678118654752440f

#define TS 32
#define KC 64
#define KSPLIT (DIM / KC)       // 16
#define NBLK_RED 64             // reduce_final grid

typedef float f2 __attribute__((ext_vector_type(2)));   // (re, im)

__device__ __forceinline__ f2 cmul(f2 a, f2 b) {
    return (f2){a.x * b.x - a.y * b.y, a.x * b.y + a.y * b.x};
}

// ---------------------------------------------------------------------------
// Kernel A: psi(x) = F(x, params)|0>. 256 threads = 1 point/block.
// Radix-4 formulation of the proven r11 fused-U circuit (absmax 0.0):
//   per block: [4x4 local Kronecker] [3x radix-4 shuffle] [transpose]
//              [4x4 local] [CRZ via cis tables]  == 7 dependent rounds
// Layout ping-pong per block (A: d = w*256+lane*4+m ; B: d = m*256+lane*4+w).
// Qubit q <-> d-bit 9-q; lane bit l <-> qubit 7-l (both layouts).
// Block 0 is collapsed: |0> -> product state directly in layout B.
// ALL sincos precomputed in staging; main loop is pure VALU/LDS/shuffle.
// ---------------------------------------------------------------------------
__global__ __launch_bounds__(256)
void states_kernel(const float* __restrict__ data,
                   const float* __restrict__ params,
                   float2* __restrict__ psi,
                   double* __restrict__ acc,
                   int* __restrict__ cnt)
{
    __shared__ f2    Tb[2][16 * 64];   // ping-pong transpose buffers
    __shared__ f2    UT[NB * NQ * 4];  // U_q = RY RZ H 2x2 per (block,qubit)
    __shared__ f2    Kt[NB * 2 * 16];  // 4x4 Kronecker: side0=U8(x)U9, side1=U0(x)U1
    __shared__ f2    Ct[NB * 3 * 16];  // radix-4 shuffle coeffs [j][pair][combo][t]
    __shared__ f2    Gt[NB * 64];      // CRZ cis(g(m,w,b7,b2)), parity-matched layout
    __shared__ f2    Lt[NB * 64];      // CRZ cis(laneOnly(lane))
    __shared__ float sCrz[NB * NQ];    // CRZ angles

    const int tid  = threadIdx.x;
    const int w    = tid >> 6;          // 0..3
    const int lane = tid & 63;
    const int pt   = blockIdx.x;

    if (pt == 0 && tid == 0) { acc[0] = 0.0; acc[1] = 0.0; cnt[0] = 0; }

    // ---------------- staging phase 1: U matrices + CRZ angles ----------------
    if (tid < NB * NQ) {
        const int j = tid / NQ, q = tid - j * NQ;
        float c, s;
        __sincosf(0.5f * params[j * 2 * NQ + q], &s, &c);
        float cx, sx;
        __sincosf(0.5f * data[pt * (NB * NQ) + tid], &sx, &cx);
        const float al = (c - s) * S2, be = (c + s) * S2;
        f2* u = &UT[tid * 4];
        u[0] = (f2){ al * cx, -be * sx};   // U[0][0]
        u[1] = (f2){ be * cx, -al * sx};   // U[0][1]
        u[2] = (f2){ be * cx,  al * sx};   // U[1][0]
        u[3] = (f2){-al * cx, -be * sx};   // U[1][1]
        sCrz[tid] = params[j * 2 * NQ + NQ + q];
    }
    __syncthreads();

    // ---------------- staging phase 2: derived tables ----------------
    // Kt: e = j*32 + side*16 + a*4 + b
    for (int e = tid; e < NB * 2 * 16; e += 256) {
        const int j = e >> 5, side = (e >> 4) & 1, a = (e >> 2) & 3, b = e & 3;
        const int qh = side ? 0 : 8, ql = side ? 1 : 9;
        Kt[e] = cmul(UT[(j * NQ + qh) * 4 + ((a >> 1) * 2 + (b >> 1))],
                     UT[(j * NQ + ql) * 4 + ((a & 1) * 2 + (b & 1))]);
    }
    // Ct: e = j*48 + p*16 + combo*4 + t ; pair p merges lane bits (2p, 2p+1)
    for (int e = tid; e < NB * 3 * 16; e += 256) {
        const int j = e / 48, r = e - j * 48;
        const int p = r >> 4, k = r & 15, combo = k >> 2, t = k & 3;
        const int la = combo & 1, lb = (combo >> 1) & 1;
        const int ta = t & 1, tb = (t >> 1) & 1;
        const int qa = 7 - 2 * p, qb = 6 - 2 * p;
        Ct[e] = cmul(UT[(j * NQ + qa) * 4 + (la * 2 + (la ^ ta))],
                     UT[(j * NQ + qb) * 4 + (lb * 2 + (lb ^ tb))]);
    }
    // Gt: e = j*64 + (m<<4)|(w<<2)|(b7<<1)|b2 ; even j -> layout B, odd -> A
    for (int e = tid; e < NB * 64; e += 256) {
        const int j = e >> 6, r = e & 63;
        const float m1 = (float)((r >> 5) & 1), m0 = (float)((r >> 4) & 1);
        const float w1 = (float)((r >> 3) & 1), w0 = (float)((r >> 2) & 1);
        const float b7 = (float)((r >> 1) & 1), b2 = (float)(r & 1);
        const float* phi = &sCrz[j * NQ];
        float g;
        if ((j & 1) == 0)   // layout B: b9b8 = m bits, b1b0 = w bits
            g = phi[0] * m1 * (m0 - 0.5f) + phi[1] * m0 * (b7 - 0.5f)
              + phi[7] * b2 * (w1 - 0.5f) + phi[8] * w1 * (w0 - 0.5f)
              + phi[9] * w0 * (m1 - 0.5f);
        else                 // layout A: b9b8 = w bits, b1b0 = m bits
            g = phi[0] * w1 * (w0 - 0.5f) + phi[1] * w0 * (b7 - 0.5f)
              + phi[7] * b2 * (m1 - 0.5f) + phi[8] * m1 * (m0 - 0.5f)
              + phi[9] * m0 * (w1 - 0.5f);
        float s, c;
        __sincosf(g, &s, &c);
        Gt[e] = (f2){c, s};
    }
    // Lt: e = j*64 + lane ; laneOnly(lane) identical in both layouts
    for (int e = tid; e < NB * 64; e += 256) {
        const int j = e >> 6, ln = e & 63;
        const float B2 = (float)( ln       & 1), B3 = (float)((ln >> 1) & 1);
        const float B4 = (float)((ln >> 2) & 1), B5 = (float)((ln >> 3) & 1);
        const float B6 = (float)((ln >> 4) & 1), B7 = (float)((ln >> 5) & 1);
        const float* phi = &sCrz[j * NQ];
        const float lo = phi[2] * B7 * (B6 - 0.5f) + phi[3] * B6 * (B5 - 0.5f)
                       + phi[4] * B5 * (B4 - 0.5f) + phi[5] * B4 * (B3 - 0.5f)
                       + phi[6] * B3 * (B2 - 0.5f);
        float s, c;
        __sincosf(lo, &s, &c);
        Lt[e] = (f2){c, s};
    }
    __syncthreads();

    const int b72 = ((((lane >> 5) & 1)) << 1) | (lane & 1);   // (b7<<1)|b2

    #define LOCAL4(j, side) { \
        const f2* Km = &Kt[((j) * 2 + (side)) * 16]; \
        f2 n0 = cmul(Km[ 0], v[0]) + cmul(Km[ 1], v[1]) + cmul(Km[ 2], v[2]) + cmul(Km[ 3], v[3]); \
        f2 n1 = cmul(Km[ 4], v[0]) + cmul(Km[ 5], v[1]) + cmul(Km[ 6], v[2]) + cmul(Km[ 7], v[3]); \
        f2 n2 = cmul(Km[ 8], v[0]) + cmul(Km[ 9], v[1]) + cmul(Km[10], v[2]) + cmul(Km[11], v[3]); \
        f2 n3 = cmul(Km[12], v[0]) + cmul(Km[13], v[1]) + cmul(Km[14], v[2]) + cmul(Km[15], v[3]); \
        v[0] = n0; v[1] = n1; v[2] = n2; v[3] = n3; }

    #define SHUF4(j, p) { \
        const int sh = 2 * (p); \
        const int combo = (((lane >> (sh + 1)) & 1) << 1) | ((lane >> sh) & 1); \
        const f2* Cm = &Ct[((j) * 3 + (p)) * 16 + combo * 4]; \
        const f2 c0 = Cm[0], c1 = Cm[1], c2 = Cm[2], c3 = Cm[3]; \
        _Pragma("unroll") \
        for (int m = 0; m < 4; ++m) { \
            const f2 x = v[m]; \
            const f2 p1 = { __shfl_xor(x.x, 1 << sh, 64), __shfl_xor(x.y, 1 << sh, 64) }; \
            const f2 p2 = { __shfl_xor(x.x, 2 << sh, 64), __shfl_xor(x.y, 2 << sh, 64) }; \
            const f2 p3 = { __shfl_xor(x.x, 3 << sh, 64), __shfl_xor(x.y, 3 << sh, 64) }; \
            v[m] = cmul(c0, x) + cmul(c1, p1) + cmul(c2, p2) + cmul(c3, p3); \
        } }

    #define TRANSPOSE(buf) { \
        f2* T = Tb[buf]; \
        _Pragma("unroll") \
        for (int m = 0; m < 4; ++m) T[(w * 4 + m) * 64 + lane] = v[m]; \
        __syncthreads(); \
        f2 nv0 = T[(0 * 4 + w) * 64 + lane]; \
        f2 nv1 = T[(1 * 4 + w) * 64 + lane]; \
        f2 nv2 = T[(2 * 4 + w) * 64 + lane]; \
        f2 nv3 = T[(3 * 4 + w) * 64 + lane]; \
        v[0] = nv0; v[1] = nv1; v[2] = nv2; v[3] = nv3; }

    #define CRZ4(j) { \
        const f2 l = Lt[((j) << 6) | lane]; \
        _Pragma("unroll") \
        for (int m = 0; m < 4; ++m) { \
            const f2 g = Gt[((j) << 6) | (m << 4) | (w << 2) | b72]; \
            v[m] = cmul(v[m], cmul(l, g)); \
        } }

    // ---- block 0 collapsed: |0> -> product state directly in layout B ----
    // layout B bits: s0=m1 s1=m0 s2..s7 = lane bits 5..0, s8=w1, s9=w0
    f2 v[4];
    {
        f2 f = UT[2 * 4 + ((lane >> 5) & 1) * 2];            // U2[s2][0]
        #pragma unroll
        for (int q = 3; q <= 7; ++q)
            f = cmul(f, UT[q * 4 + ((lane >> (7 - q)) & 1) * 2]);
        f = cmul(f, UT[8 * 4 + ((w >> 1) & 1) * 2]);
        f = cmul(f, UT[9 * 4 + (w & 1) * 2]);
        #pragma unroll
        for (int m = 0; m < 4; ++m)
            v[m] = cmul(cmul(UT[0 * 4 + ((m >> 1) & 1) * 2],
                             UT[1 * 4 + (m & 1) * 2]), f);
    }
    CRZ4(0)     // even parity table = layout B ✓

    // ---- blocks 1..9 ----
    #pragma unroll
    for (int j = 1; j < NB; ++j) {
        if (j & 1) {            // layout B at entry
            LOCAL4(j, 1)        // qubits 0,1 on m
            SHUF4(j, 0) SHUF4(j, 1) SHUF4(j, 2)
            TRANSPOSE(j & 1)    // B -> A
            LOCAL4(j, 0)        // qubits 8,9 on m
            CRZ4(j)             // odd parity table = layout A ✓
        } else {                // layout A at entry
            LOCAL4(j, 0)
            SHUF4(j, 0) SHUF4(j, 1) SHUF4(j, 2)
            TRANSPOSE(j & 1)    // A -> B
            LOCAL4(j, 1)
            CRZ4(j)             // even parity table = layout B ✓
        }
    }

    // ---- write out (NB-1=9 odd -> final layout A: d = w*256+lane*4+m) ----
    float2* o = psi + (size_t)pt * DIM + w * 256 + lane * 4;
    *(float4*)&o[0] = make_float4(v[0].x, v[0].y, v[1].x, v[1].y);
    *(float4*)&o[2] = make_float4(v[2].x, v[2].y, v[3].x, v[3].y);
}

// ---------------------------------------------------------------------------
// Kernel B: tiled complex Gram (proven rounds 2/5/6/8-11). 32x32 tile x 16
// K-chunks = 256 blocks. Coalesced float4 staging; A broadcast / Bt <=2-way
// LDS reads; 2x2 register accumulator per thread.
// ---------------------------------------------------------------------------
__global__ __launch_bounds__(256)
void gram_kernel(const float2* __restrict__ psi, float2* __restrict__ Gpart)
{
    __shared__ float2 A [TS][KC + 2];   // pitch 66 float2
    __shared__ float2 Bt[KC][TS + 2];   // pitch 34 float2

    const int tid  = threadIdx.x;
    const int bx   = blockIdx.x;
    const int ks   = bx & 15;
    const int tile = bx >> 4;
    const int ti   = tile >> 2, tj = tile & 3;
    const int kbase = ks * KC;

    #pragma unroll
    for (int it = 0; it < 2; ++it) {
        const int slot = it * 256 + tid;
        const int row  = slot >> 4;          // 0..31
        const int kq   = (slot & 15) << 2;   // 0,4,...,60
        const float4* sa = (const float4*)(psi + (ti * TS + row) * DIM + kbase + kq);
        const float4 a01 = sa[0], a23 = sa[1];
        *(float4*)&A[row][kq]     = a01;
        *(float4*)&A[row][kq + 2] = a23;
        const float4* sb = (const float4*)(psi + (tj * TS + row) * DIM + kbase + kq);
        const float4 b01 = sb[0], b23 = sb[1];
        Bt[kq + 0][row] = make_float2(b01.x, b01.y);
        Bt[kq + 1][row] = make_float2(b01.z, b01.w);
        Bt[kq + 2][row] = make_float2(b23.x, b23.y);
        Bt[kq + 3][row] = make_float2(b23.z, b23.w);
    }
    __syncthreads();

    const int ty = tid >> 4, tx = tid & 15;
    float g00r = 0.f, g00i = 0.f, g01r = 0.f, g01i = 0.f;
    float g10r = 0.f, g10i = 0.f, g11r = 0.f, g11i = 0.f;

    #pragma unroll 4
    for (int k = 0; k < KC; k += 2) {
        const float4 a0 = *(const float4*)&A[2 * ty    ][k];
        const float4 a1 = *(const float4*)&A[2 * ty + 1][k];
        const float4 b0 = *(const float4*)&Bt[k    ][2 * tx];
        const float4 b1 = *(const float4*)&Bt[k + 1][2 * tx];
        g00r += a0.x * b0.x + a0.y * b0.y;  g00i += a0.x * b0.y - a0.y * b0.x;
        g01r += a0.x * b0.z + a0.y * b0.w;  g01i += a0.x * b0.w - a0.y * b0.z;
        g10r += a1.x * b0.x + a1.y * b0.y;  g10i += a1.x * b0.y - a1.y * b0.x;
        g11r += a1.x * b0.z + a1.y * b0.w;  g11i += a1.x * b0.w - a1.y * b0.z;
        g00r += a0.z * b1.x + a0.w * b1.y;  g00i += a0.z * b1.y - a0.w * b1.x;
        g01r += a0.z * b1.z + a0.w * b1.w;  g01i += a0.z * b1.w - a0.w * b1.z;
        g10r += a1.z * b1.x + a1.w * b1.y;  g10i += a1.z * b1.y - a1.w * b1.x;
        g11r += a1.z * b1.z + a1.w * b1.w;  g11i += a1.z * b1.w - a1.w * b1.z;
    }

    float2* gp = Gpart + ks * (NPTS * NPTS);
    const int gr0 = ti * TS + 2 * ty, gc0 = tj * TS + 2 * tx;
    gp[(gr0    ) * NPTS + gc0    ] = make_float2(g00r, g00i);
    gp[(gr0    ) * NPTS + gc0 + 1] = make_float2(g01r, g01i);
    gp[(gr0 + 1) * NPTS + gc0    ] = make_float2(g10r, g10i);
    gp[(gr0 + 1) * NPTS + gc0 + 1] = make_float2(g11r, g11i);
}

// ---------------------------------------------------------------------------
// Kernel C: sum K-partials (coalesced), K = |G|^2, reduce polarity & sum(K^2);
// last-finishing block (atomic counter, proven) writes the scalar.
// ---------------------------------------------------------------------------
__global__ __launch_bounds__(256)
void reduce_final(const float2* __restrict__ Gpart,
                  const float* __restrict__ labels,
                  double* __restrict__ acc,
                  int* __restrict__ cnt,
                  float* __restrict__ out)
{
    const int idx = blockIdx.x * 256 + threadIdx.x;   // 0..16383
    float gr = 0.f, gi = 0.f;
    #pragma unroll
    for (int p = 0; p < KSPLIT; ++p) {
        const float2 g = Gpart[p * (NPTS * NPTS) + idx];
        gr += g.x; gi += g.y;
    }
    const int i  = idx >> 7;
    const int jj = idx & (NPTS - 1);
    const float K = gr * gr + gi * gi;
    double pol = (double)(labels[i] * labels[jj]) * (double)K;
    double k2  = (double)K * (double)K;
    #pragma unroll
    for (int off = 1; off < 64; off <<= 1) {
        pol += __shfl_xor(pol, off, 64);
        k2  += __shfl_xor(k2,  off, 64);
    }
    __shared__ double sp[4], sk[4];
    const int wv = threadIdx.x >> 6;
    if ((threadIdx.x & 63) == 0) { sp[wv] = pol; sk[wv] = k2; }
    __syncthreads();
    if (threadIdx.x == 0) {
        atomicAdd(&acc[0], sp[0] + sp[1] + sp[2] + sp[3]);
        atomicAdd(&acc[1], sk[0] + sk[1] + sk[2] + sk[3]);
        __threadfence();
        const int done = atomicAdd(cnt, 1);
        if (done == NBLK_RED - 1) {
            const double p  = atomicAdd(&acc[0], 0.0);   // atomic read
            const double s2 = atomicAdd(&acc[1], 0.0);
            double sumL2 = 0.0;
            for (int t = 0; t < NPTS; ++t) {
                const double l = (double)labels[t];
                sumL2 += l * l;
            }
            out[0] = (float)(p / (sumL2 * sqrt(s2)));
        }
    }
}

// ---------------------------------------------------------------------------
extern "C" void kernel_launch(void* const* d_in, const int* in_sizes, int n_in,
                              void* d_out, int out_size, void* d_ws, size_t ws_size,
                              hipStream_t stream)
{
    const float* data   = (const float*)d_in[0];   // [128,100]
    const float* labels = (const float*)d_in[1];   // [128]
    const float* params = (const float*)d_in[2];   // [10,2,10]
    float* out = (float*)d_out;

    float2* psi   = (float2*)d_ws;                                   // 1 MiB
    float2* Gpart = (float2*)((char*)d_ws + (size_t)(1u << 20));     // 2 MiB
    double* acc   = (double*)((char*)d_ws + (size_t)(3u << 20));     // 16 B
    int*    cnt   = (int*)   ((char*)d_ws + (size_t)(3u << 20) + 16);

    states_kernel<<<NPTS, 256, 0, stream>>>(data, params, psi, acc, cnt);
    gram_kernel<<<256, 256, 0, stream>>>(psi, Gpart);
    reduce_final<<<NBLK_RED, 256, 0, stream>>>(Gpart, labels, acc, cnt, out);
}